// Round 10
// baseline (186.080 us; speedup 1.0000x reference)
//
#include <hip/hip_runtime.h>

typedef unsigned int uint;
typedef unsigned short ushort;
typedef __attribute__((ext_vector_type(8))) short short8;   // 8 bf16 = 4 VGPRs
typedef __attribute__((ext_vector_type(4))) float floatx4;  // MFMA C/D

#define N_NODES 50000
#define N_EDGES 1600000
#define DIM 128
#define LN_EPS 1e-10f

#define NB2 1564                 // half-buckets of 32 rows: ceil(50000/32)
#define CAP2 1280                // mean 1024, +8 sigma
#define EPB 6250                 // edges per scatter block (256*6250 = 1.6M exact)
#define SB 256                   // scatter blocks
#define CONVB 256                // grid-stride convert blocks fused into prep
#define CAPR 76                  // per-row agg list slots (mean 32, +7.8 sigma)

__device__ __forceinline__ uint f2bf(float x) {
    uint u = __float_as_uint(x);
    return (u + 0x7FFFu + ((u >> 16) & 1u)) >> 16;   // RNE to bf16
}

// ---------------------------------------------------------------------------
// prep (R28 = R24 verbatim -- the measured-best prep; rest=110.3us).  Seven
// prep variants (staged/direct/split/atomic-free) landed rest in 110-122us
// with the 3-dispatch fused forms at the 110 floor: rest is dominated by a
// fixed per-iteration cost, not prep internals.  Fused scatter + grid-stride
// convert, register edge stash, 69 KB LDS -> 2 blocks/CU, line-rotated
// phase-B reservation atomics (R27 proved contention here is ~free).
// Phase A histogram atomicAdd return value = edge's rank within its bin;
// phase C places at lbase[b]+rank; phase D flushes in slot order ==
// destination order (full-line clustered perm writes).
// ---------------------------------------------------------------------------
__global__ __launch_bounds__(1024, 8) void prep(
    const float* __restrict__ feat, const float* __restrict__ W,
    const int* __restrict__ rows, const int* __restrict__ cols,
    const float* __restrict__ vals, int* __restrict__ gcnt,
    int2* __restrict__ perm, uint* __restrict__ featb_u,
    ushort* __restrict__ wbf)
{
    __shared__ int  cnt[NB2];           // 6.3 KB
    __shared__ int  gbase[NB2];         // 6.3 KB
    __shared__ int  lbase[NB2];         // 6.3 KB
    __shared__ int  csum[64];
    __shared__ int2 stageE[EPB];        // 50 KB   (total 69 KB -> 2 blocks/CU)
    const int bx = blockIdx.x;
    const int t  = threadIdx.x;

    if (bx >= SB) {                      // ---- fused convert (no LDS use) ----
        const int cb = bx - SB;
        const int stride = CONVB * 1024;
        for (int i = cb * 1024 + t; i < N_NODES * DIM / 4; i += stride) {
            float4 v = ((const float4*)feat)[i];
            ((uint2*)featb_u)[i] = make_uint2(
                f2bf(v.x) | (f2bf(v.y) << 16),
                f2bf(v.z) | (f2bf(v.w) << 16));
        }
        for (int i = cb * 1024 + t; i < DIM * DIM / 4; i += stride) {
            float4 v = ((const float4*)W)[i];
            ushort4 o;
            o.x = (ushort)f2bf(v.x); o.y = (ushort)f2bf(v.y);
            o.z = (ushort)f2bf(v.z); o.w = (ushort)f2bf(v.w);
            ((ushort4*)wbf)[i] = o;
        }
        return;
    }

    // ---- phase A: rows -> rank-within-bin, stashed in registers ----
    for (int i = t; i < NB2; i += 1024) cnt[i] = 0;
    __syncthreads();
    const int base = bx * EPB;
    uint pk[7];                          // EPB = 6*1024 + 106
    #pragma unroll
    for (int i = 0; i < 7; ++i) {
        int k = i * 1024 + t;
        if (k < EPB) {
            int r = rows[base + k];
            int rank = atomicAdd(&cnt[r >> 5], 1);  // rank < 6250 (13 bits)
            pk[i] = ((uint)rank << 16) | (uint)r;   // r < 50000 (16 bits)
        }
    }
    __syncthreads();

    // ---- phase B: global reservation (line-rotated) + LDS scan (64x25) ----
    {
        const int rot = (bx * 16) % NB2;             // 64 B line offset/block
        for (int i = t; i < NB2; i += 1024) {
            int ii = i + rot; if (ii >= NB2) ii -= NB2;
            int c = cnt[ii];
            gbase[ii] = c ? atomicAdd(&gcnt[ii], c) : 0;
        }
    }
    if (t < 64) {
        int s = 0;
        for (int j = 0; j < 25; ++j) {
            int idx = t * 25 + j;
            if (idx < NB2) s += cnt[idx];
        }
        csum[t] = s;
    }
    __syncthreads();
    if (t == 0) {
        int s = 0;
        for (int i = 0; i < 64; ++i) { int c = csum[i]; csum[i] = s; s += c; }
    }
    __syncthreads();
    if (t < 64) {
        int run = csum[t];
        for (int j = 0; j < 25; ++j) {
            int idx = t * 25 + j;
            if (idx < NB2) { lbase[idx] = run; run += cnt[idx]; }
        }
    }
    __syncthreads();

    // ---- phase C: stage grouped by bin -- atomic-free placement ----
    // pack: col (16b) | local row r&31 (5b, bits 16-20) | bin (11b, bits 21-31)
    #pragma unroll
    for (int i = 0; i < 7; ++i) {
        int k = i * 1024 + t;
        if (k < EPB) {
            uint s = pk[i];
            int r = (int)(s & 0xFFFFu);
            int rank = (int)(s >> 16);
            int b = r >> 5;
            int pos = lbase[b] + rank;
            stageE[pos] = make_int2(
                (uint)cols[base + k] | ((uint)(r & 31) << 16) | ((uint)b << 21),
                __float_as_int(vals[base + k]));
        }
    }
    __syncthreads();

    // ---- phase D: clustered flush (slot order == destination order) ----
    for (int j = t; j < EPB; j += 1024) {
        int2 p = stageE[j];
        uint b = ((uint)p.x) >> 21;
        int pos = gbase[b] + (j - lbase[b]);
        if (pos < CAP2)                 // statistically impossible; safety
            perm[(size_t)b * CAP2 + pos] = p;       // agg masks b bits
    }
}

// ---------------------------------------------------------------------------
// agg_fused (R28): R24 structure with ONE change -- P2 uses PAIRED-EDGE
// gathers.  Old: 64 lanes x 4B = one 256B feat row per instruction (12-deep
// = 24 lines in flight/wave).  New: lanes 0-31 = edge A, lanes 32-63 =
// edge B, each lane loads uint2 (4 bf16 elems) -> one instruction covers
// TWO edges; 8-deep chunk = 16 edges / 32 lines in flight (+33%) at half
// the issue slots.  Each half accumulates 4 elems/lane; one shfl_xor(32)
// merges halves per row; results packed to bf16 immediately (VGPR control);
// P3 writes the quad from lanes 0-31.  P4/P5/P1 byte-identical to R24.
// ---------------------------------------------------------------------------
__global__ __launch_bounds__(512, 8) void agg_fused(
    const int2* __restrict__ perm, const int* __restrict__ gcnt,
    const ushort* __restrict__ featb, const ushort* __restrict__ wbf,
    const float* __restrict__ bias, const float* __restrict__ scale,
    const float* __restrict__ offset, float* __restrict__ out)
{
    __shared__ int2 lists[32 * CAPR];    // 19456 B union:
    ushort* rowsbuf = (ushort*)lists;    //   P3/P4: 32 x 136 bf16 (8704 B)
    float*  Cbuf    = (float*)lists;     //   P5:    32 x 132 fp32 (16896 B)
    __shared__ int  lcnt[32];

    const int t = threadIdx.x;

    // bijective XCD-chunked swizzle: each XCD gets a contiguous bin range
    const int q = NB2 >> 3, rr = NB2 & 7;
    const int xcd = blockIdx.x & 7, within = blockIdx.x >> 3;
    const int hb = (xcd < rr ? xcd * (q + 1) : rr * (q + 1) + (xcd - rr) * q) + within;

    if (t < 32) lcnt[t] = 0;
    __syncthreads();

    int n = gcnt[hb];
    if (n > CAP2) n = CAP2;
    const int2* pb = perm + (size_t)hb * CAP2;

    // ---- P1: compaction (store byte offset col<<8 for cheap P2 addr) ----
    for (int e = t; e < n; e += 512) {
        int2 p = pb[e];
        int rl = (p.x >> 16) & 31;
        int pos = atomicAdd(&lcnt[rl], 1);
        if (pos < CAPR)
            lists[rl * CAPR + pos] = make_int2((p.x & 0xFFFF) << 8, p.y);
    }
    __syncthreads();

    const int lane = t & 63;
    const int wid  = t >> 6;        // 0..7
    const int rb   = wid * 4;       // this wave's first local row
    const int hi   = lane >> 5;     // 0 = edge-A half, 1 = edge-B half
    const char* fbase = (const char*)featb;
    const uint  lane8 = (uint)(lane & 31) << 3;   // byte offset within row

    // ---- P2: paired-edge gather + accumulate.  Lane holds feat elems
    //      4*(lane&31) .. +3 of its half's edge; shfl_xor(32) merges. ----
    uint pk0[4], pk1[4];
    #pragma unroll
    for (int j = 0; j < 4; ++j) {
        int rl = rb + j;
        int cnt = lcnt[rl];
        if (cnt > CAPR) cnt = CAPR;
        const int2* L = &lists[rl * CAPR];
        float s0 = 0.f, s1 = 0.f, s2 = 0.f, s3 = 0.f;
        int e = 0;
        for (; e + 15 < cnt; e += 16) {          // 8 instr = 16 edges in flight
            int2 p[8]; uint2 g[8];
            #pragma unroll
            for (int k = 0; k < 8; ++k) p[k] = L[e + 2 * k + hi];
            #pragma unroll
            for (int k = 0; k < 8; ++k)
                g[k] = *(const uint2*)(fbase + ((uint)p[k].x + lane8));
            #pragma unroll
            for (int k = 0; k < 8; ++k) {
                float v = __int_as_float(p[k].y);
                s0 = fmaf(v, __uint_as_float(g[k].x << 16), s0);
                s1 = fmaf(v, __uint_as_float(g[k].x & 0xFFFF0000u), s1);
                s2 = fmaf(v, __uint_as_float(g[k].y << 16), s2);
                s3 = fmaf(v, __uint_as_float(g[k].y & 0xFFFF0000u), s3);
            }
        }
        for (; e + 1 < cnt; e += 2) {            // pair tail
            int2 p = L[e + hi];
            uint2 g = *(const uint2*)(fbase + ((uint)p.x + lane8));
            float v = __int_as_float(p.y);
            s0 = fmaf(v, __uint_as_float(g.x << 16), s0);
            s1 = fmaf(v, __uint_as_float(g.x & 0xFFFF0000u), s1);
            s2 = fmaf(v, __uint_as_float(g.y << 16), s2);
            s3 = fmaf(v, __uint_as_float(g.y & 0xFFFF0000u), s3);
        }
        if (e < cnt) {                           // singleton tail: hi half inert
            int2 p = L[e];
            uint2 g = *(const uint2*)(fbase + ((uint)p.x + lane8));
            float v = hi ? 0.0f : __int_as_float(p.y);
            s0 = fmaf(v, __uint_as_float(g.x << 16), s0);
            s1 = fmaf(v, __uint_as_float(g.x & 0xFFFF0000u), s1);
            s2 = fmaf(v, __uint_as_float(g.y << 16), s2);
            s3 = fmaf(v, __uint_as_float(g.y & 0xFFFF0000u), s3);
        }
        s0 += __shfl_xor(s0, 32, 64);            // merge A/B halves
        s1 += __shfl_xor(s1, 32, 64);
        s2 += __shfl_xor(s2, 32, 64);
        s3 += __shfl_xor(s3, 32, 64);
        pk0[j] = f2bf(s0) | (f2bf(s1) << 16);    // pack now: VGPR control
        pk1[j] = f2bf(s2) | (f2bf(s3) << 16);
    }
    __syncthreads();               // lists dead

    // ---- P3: lanes 0-31 write their elem quad (8B) per row, true order ----
    if (hi == 0) {
        #pragma unroll
        for (int j = 0; j < 4; ++j)
            *(uint2*)&rowsbuf[(rb + j) * 136 + 4 * lane] =
                make_uint2(pk0[j], pk1[j]);
    }
    __syncthreads();

    // ---- P4: MFMA GEMM.  D[m][n] = sum_k A[m][k] * W[n][k] ----
    const int l15  = lane & 15;
    const int quad = lane >> 4;
    const int n0   = wid * 16 + l15;       // this wave's N-column
    const float bb = bias[n0];

    floatx4 acc0 = {0.f, 0.f, 0.f, 0.f};   // m-tile 0 (rows 0..15)
    floatx4 acc1 = {0.f, 0.f, 0.f, 0.f};   // m-tile 1 (rows 16..31)
    #pragma unroll
    for (int kt = 0; kt < 4; ++kt) {
        int k0 = kt * 32 + quad * 8;
        short8 af0 = *(const short8*)&rowsbuf[l15 * 136 + k0];
        short8 af1 = *(const short8*)&rowsbuf[(l15 + 16) * 136 + k0];
        short8 bf  = *(const short8*)&wbf[n0 * DIM + k0];   // B[k][n]=W[n][k]
        acc0 = __builtin_amdgcn_mfma_f32_16x16x32_bf16(af0, bf, acc0, 0, 0, 0);
        acc1 = __builtin_amdgcn_mfma_f32_16x16x32_bf16(af1, bf, acc1, 0, 0, 0);
    }
    __syncthreads();               // rowsbuf dead

    // C/D layout: lane holds D[m=quad*4+r][n=l15] -> stage to Cbuf (+bias)
    #pragma unroll
    for (int r = 0; r < 4; ++r) {
        int m = quad * 4 + r;
        Cbuf[m * 132 + n0]        = acc0[r] + bb;
        Cbuf[(m + 16) * 132 + n0] = acc1[r] + bb;
    }
    __syncthreads();

    // ---- P5: ReLU + LN + scale/offset -> out (4 rows per wave) ----
    const float sc0 = scale[lane],  sc1 = scale[lane + 64];
    const float of0 = offset[lane], of1 = offset[lane + 64];

    #pragma unroll
    for (int j = 0; j < 4; ++j) {
        int rl = rb + j;
        int r  = hb * 32 + rl;
        if (r >= N_NODES) continue;                       // wave-uniform
        float A0 = fmaxf(Cbuf[rl * 132 + lane],      0.0f);
        float A1 = fmaxf(Cbuf[rl * 132 + lane + 64], 0.0f);

        float s = A0 + A1;
        #pragma unroll
        for (int off = 32; off >= 1; off >>= 1) s += __shfl_xor(s, off, 64);
        float mean = s * (1.0f / 128.0f);

        float d0 = A0 - mean, d1 = A1 - mean;
        float q2 = d0 * d0 + d1 * d1;
        #pragma unroll
        for (int off = 32; off >= 1; off >>= 1) q2 += __shfl_xor(q2, off, 64);
        float rstd = rsqrtf(q2 * (1.0f / 128.0f) + LN_EPS);

        size_t rowp = (size_t)r * DIM;
        out[rowp + lane]      = d0 * sc0 * rstd + of0;
        out[rowp + lane + 64] = d1 * sc1 * rstd + of1;
    }
}

extern "C" void kernel_launch(void* const* d_in, const int* in_sizes, int n_in,
                              void* d_out, int out_size, void* d_ws, size_t ws_size,
                              hipStream_t stream) {
    const float* feat_in = (const float*)d_in[0];
    const int*   rows    = (const int*)d_in[1];
    const int*   cols    = (const int*)d_in[2];
    const float* vals    = (const float*)d_in[3];
    const float* W       = (const float*)d_in[4];
    const float* bias    = (const float*)d_in[5];
    const float* scale   = (const float*)d_in[6];
    const float* offset  = (const float*)d_in[7];
    float* out = (float*)d_out;

    // ---- workspace layout ----
    char* p = (char*)d_ws;
    int2* perm = (int2*)p;                 p += (size_t)NB2 * CAP2 * 8;        // 16.0 MB
    ushort* featb = (ushort*)p;            p += (size_t)N_NODES * DIM * 2;     // 12.8 MB
    ushort* wbf = (ushort*)p;              p += DIM * DIM * 2;                 // 32 KB
    int*  gcnt = (int*)p;                  p += (size_t)(NB2 + 64) * 4;        // 6.4 KB

    hipMemsetAsync(gcnt, 0, (size_t)NB2 * sizeof(int), stream);

    prep<<<SB + CONVB, 1024, 0, stream>>>(feat_in, W, rows, cols, vals,
                                          gcnt, perm, (uint*)featb, wbf);
    agg_fused<<<NB2, 512, 0, stream>>>(perm, gcnt, featb, wbf,
                                       bias, scale, offset, out);
}

// Round 11
// 176.587 us; speedup vs baseline: 1.0538x; 1.0538x over previous
//
#include <hip/hip_runtime.h>

typedef unsigned int uint;
typedef unsigned short ushort;
typedef __attribute__((ext_vector_type(8))) short short8;   // 8 bf16 = 4 VGPRs
typedef __attribute__((ext_vector_type(4))) float floatx4;  // MFMA C/D

#define N_NODES 50000
#define N_EDGES 1600000
#define DIM 128
#define LN_EPS 1e-10f

#define NB2 1564                 // half-buckets of 32 rows: ceil(50000/32)
#define CAP2 1280                // mean 1024, +8 sigma
#define EPB 6250                 // edges per scatter block (256*6250 = 1.6M exact)
#define SB 256                   // scatter blocks
#define CONVB 256                // grid-stride convert blocks fused into prep
#define CAPR 76                  // per-row agg list slots (mean 32, +7.8 sigma)

__device__ __forceinline__ uint f2bf(float x) {
    uint u = __float_as_uint(x);
    return (u + 0x7FFFu + ((u >> 16) & 1u)) >> 16;   // RNE to bf16
}

// ---------------------------------------------------------------------------
// prep (R29 = R24 verbatim -- the measured-best prep; rest=110.3us).  Seven
// prep variants (staged/direct/split/atomic-free) landed rest in 110-122us
// with the 3-dispatch fused forms at the 110 floor: rest is dominated by a
// fixed per-iteration cost, not prep internals.  Fused scatter + grid-stride
// convert, register edge stash, 69 KB LDS -> 2 blocks/CU, line-rotated
// phase-B reservation atomics (R27 proved contention here is ~free).
// ---------------------------------------------------------------------------
__global__ __launch_bounds__(1024, 8) void prep(
    const float* __restrict__ feat, const float* __restrict__ W,
    const int* __restrict__ rows, const int* __restrict__ cols,
    const float* __restrict__ vals, int* __restrict__ gcnt,
    int2* __restrict__ perm, uint* __restrict__ featb_u,
    ushort* __restrict__ wbf)
{
    __shared__ int  cnt[NB2];           // 6.3 KB
    __shared__ int  gbase[NB2];         // 6.3 KB
    __shared__ int  lbase[NB2];         // 6.3 KB
    __shared__ int  csum[64];
    __shared__ int2 stageE[EPB];        // 50 KB   (total 69 KB -> 2 blocks/CU)
    const int bx = blockIdx.x;
    const int t  = threadIdx.x;

    if (bx >= SB) {                      // ---- fused convert (no LDS use) ----
        const int cb = bx - SB;
        const int stride = CONVB * 1024;
        for (int i = cb * 1024 + t; i < N_NODES * DIM / 4; i += stride) {
            float4 v = ((const float4*)feat)[i];
            ((uint2*)featb_u)[i] = make_uint2(
                f2bf(v.x) | (f2bf(v.y) << 16),
                f2bf(v.z) | (f2bf(v.w) << 16));
        }
        for (int i = cb * 1024 + t; i < DIM * DIM / 4; i += stride) {
            float4 v = ((const float4*)W)[i];
            ushort4 o;
            o.x = (ushort)f2bf(v.x); o.y = (ushort)f2bf(v.y);
            o.z = (ushort)f2bf(v.z); o.w = (ushort)f2bf(v.w);
            ((ushort4*)wbf)[i] = o;
        }
        return;
    }

    // ---- phase A: rows -> rank-within-bin, stashed in registers ----
    for (int i = t; i < NB2; i += 1024) cnt[i] = 0;
    __syncthreads();
    const int base = bx * EPB;
    uint pk[7];                          // EPB = 6*1024 + 106
    #pragma unroll
    for (int i = 0; i < 7; ++i) {
        int k = i * 1024 + t;
        if (k < EPB) {
            int r = rows[base + k];
            int rank = atomicAdd(&cnt[r >> 5], 1);  // rank < 6250 (13 bits)
            pk[i] = ((uint)rank << 16) | (uint)r;   // r < 50000 (16 bits)
        }
    }
    __syncthreads();

    // ---- phase B: global reservation (line-rotated) + LDS scan (64x25) ----
    {
        const int rot = (bx * 16) % NB2;             // 64 B line offset/block
        for (int i = t; i < NB2; i += 1024) {
            int ii = i + rot; if (ii >= NB2) ii -= NB2;
            int c = cnt[ii];
            gbase[ii] = c ? atomicAdd(&gcnt[ii], c) : 0;
        }
    }
    if (t < 64) {
        int s = 0;
        for (int j = 0; j < 25; ++j) {
            int idx = t * 25 + j;
            if (idx < NB2) s += cnt[idx];
        }
        csum[t] = s;
    }
    __syncthreads();
    if (t == 0) {
        int s = 0;
        for (int i = 0; i < 64; ++i) { int c = csum[i]; csum[i] = s; s += c; }
    }
    __syncthreads();
    if (t < 64) {
        int run = csum[t];
        for (int j = 0; j < 25; ++j) {
            int idx = t * 25 + j;
            if (idx < NB2) { lbase[idx] = run; run += cnt[idx]; }
        }
    }
    __syncthreads();

    // ---- phase C: stage grouped by bin -- atomic-free placement ----
    // pack: col (16b) | local row r&31 (5b, bits 16-20) | bin (11b, bits 21-31)
    #pragma unroll
    for (int i = 0; i < 7; ++i) {
        int k = i * 1024 + t;
        if (k < EPB) {
            uint s = pk[i];
            int r = (int)(s & 0xFFFFu);
            int rank = (int)(s >> 16);
            int b = r >> 5;
            int pos = lbase[b] + rank;
            stageE[pos] = make_int2(
                (uint)cols[base + k] | ((uint)(r & 31) << 16) | ((uint)b << 21),
                __float_as_int(vals[base + k]));
        }
    }
    __syncthreads();

    // ---- phase D: clustered flush (slot order == destination order) ----
    for (int j = t; j < EPB; j += 1024) {
        int2 p = stageE[j];
        uint b = ((uint)p.x) >> 21;
        int pos = gbase[b] + (j - lbase[b]);
        if (pos < CAP2)                 // statistically impossible; safety
            perm[(size_t)b * CAP2 + pos] = p;       // agg masks b bits
    }
}

// ---------------------------------------------------------------------------
// agg_fused (R29): R24 P2 access pattern restored (all 64 lanes on ONE row,
// scalar 4B/lane -- R28's two-rows-per-instruction pairing cost +18us and
// +57MB fabric traffic).  ONE change vs R24: __launch_bounds__(512, 6)
// (VGPR cap ~85 vs 64) + 16-deep chunk.  Rationale: R24 reported VGPR=32,
// which cannot hold a real 12-deep pipeline (needs ~48 live regs) -- the
// compiler was re-batching to ~6-8 outstanding loads.  Deeper real pipeline
// at 3 blocks/CU (24 waves) = +50% lines in flight vs 32 shallow waves.
// P1 stores BYTE offsets (col<<8); P3 LDS stride 136; P4 MFMA 16x16x32;
// P5 fused ReLU+LN.
// ---------------------------------------------------------------------------
__global__ __launch_bounds__(512, 6) void agg_fused(
    const int2* __restrict__ perm, const int* __restrict__ gcnt,
    const ushort* __restrict__ featb, const ushort* __restrict__ wbf,
    const float* __restrict__ bias, const float* __restrict__ scale,
    const float* __restrict__ offset, float* __restrict__ out)
{
    __shared__ int2 lists[32 * CAPR];    // 19456 B union:
    ushort* rowsbuf = (ushort*)lists;    //   P3/P4: 32 x 136 bf16 (8704 B)
    float*  Cbuf    = (float*)lists;     //   P5:    32 x 132 fp32 (16896 B)
    __shared__ int  lcnt[32];

    const int t = threadIdx.x;

    // bijective XCD-chunked swizzle: each XCD gets a contiguous bin range
    const int q = NB2 >> 3, rr = NB2 & 7;
    const int xcd = blockIdx.x & 7, within = blockIdx.x >> 3;
    const int hb = (xcd < rr ? xcd * (q + 1) : rr * (q + 1) + (xcd - rr) * q) + within;

    if (t < 32) lcnt[t] = 0;
    __syncthreads();

    int n = gcnt[hb];
    if (n > CAP2) n = CAP2;
    const int2* pb = perm + (size_t)hb * CAP2;

    // ---- P1: compaction (store byte offset col<<8 for cheap P2 addr) ----
    for (int e = t; e < n; e += 512) {
        int2 p = pb[e];
        int rl = (p.x >> 16) & 31;
        int pos = atomicAdd(&lcnt[rl], 1);
        if (pos < CAPR)
            lists[rl * CAPR + pos] = make_int2((p.x & 0xFFFF) << 8, p.y);
    }
    __syncthreads();

    const int lane = t & 63;
    const int wid  = t >> 6;        // 0..7
    const int rb   = wid * 4;       // this wave's first local row
    const char* fbase = (const char*)featb;
    const uint  lane4 = (uint)lane << 2;

    // ---- P2: gather + accumulate (ax = elem 2*lane, ay = elem 2*lane+1),
    //      16 outstanding scalar gathers per chunk ----
    float ax[4], ay[4];
    #pragma unroll
    for (int j = 0; j < 4; ++j) {
        int rl = rb + j;
        int cnt = lcnt[rl];
        if (cnt > CAPR) cnt = CAPR;
        const int2* L = &lists[rl * CAPR];
        float sx = 0.f, sy = 0.f;
        int e = 0;
        for (; e + 15 < cnt; e += 16) {           // 16 outstanding gathers
            int4 q8[8]; uint g[16];
            #pragma unroll
            for (int k = 0; k < 8; ++k) q8[k] = *(const int4*)&L[e + 2 * k];
            #pragma unroll
            for (int k = 0; k < 8; ++k) {
                g[2*k]   = *(const uint*)(fbase + ((uint)q8[k].x + lane4));
                g[2*k+1] = *(const uint*)(fbase + ((uint)q8[k].z + lane4));
            }
            #pragma unroll
            for (int k = 0; k < 8; ++k) {
                float v0 = __int_as_float(q8[k].y);
                float v1 = __int_as_float(q8[k].w);
                sx = fmaf(v0, __uint_as_float(g[2*k] << 16), sx);
                sy = fmaf(v0, __uint_as_float(g[2*k] & 0xFFFF0000u), sy);
                sx = fmaf(v1, __uint_as_float(g[2*k+1] << 16), sx);
                sy = fmaf(v1, __uint_as_float(g[2*k+1] & 0xFFFF0000u), sy);
            }
        }
        for (; e + 3 < cnt; e += 4) {
            int4 q2[2]; uint g[4];
            #pragma unroll
            for (int k = 0; k < 2; ++k) q2[k] = *(const int4*)&L[e + 2 * k];
            #pragma unroll
            for (int k = 0; k < 2; ++k) {
                g[2*k]   = *(const uint*)(fbase + ((uint)q2[k].x + lane4));
                g[2*k+1] = *(const uint*)(fbase + ((uint)q2[k].z + lane4));
            }
            #pragma unroll
            for (int k = 0; k < 2; ++k) {
                float v0 = __int_as_float(q2[k].y);
                float v1 = __int_as_float(q2[k].w);
                sx = fmaf(v0, __uint_as_float(g[2*k] << 16), sx);
                sy = fmaf(v0, __uint_as_float(g[2*k] & 0xFFFF0000u), sy);
                sx = fmaf(v1, __uint_as_float(g[2*k+1] << 16), sx);
                sy = fmaf(v1, __uint_as_float(g[2*k+1] & 0xFFFF0000u), sy);
            }
        }
        for (; e < cnt; ++e) {
            int2 p = L[e];
            uint g = *(const uint*)(fbase + ((uint)p.x + lane4));
            float v = __int_as_float(p.y);
            sx = fmaf(v, __uint_as_float(g << 16), sx);
            sy = fmaf(v, __uint_as_float(g & 0xFFFF0000u), sy);
        }
        ax[j] = sx; ay[j] = sy;
    }
    __syncthreads();               // lists dead

    // ---- P3: rows -> LDS bf16 (true element order), stride 136 ushorts ----
    #pragma unroll
    for (int j = 0; j < 4; ++j) {
        uint pkd = f2bf(ax[j]) | (f2bf(ay[j]) << 16);
        *(uint*)&rowsbuf[(rb + j) * 136 + 2 * lane] = pkd;
    }
    __syncthreads();

    // ---- P4: MFMA GEMM.  D[m][n] = sum_k A[m][k] * W[n][k] ----
    const int l15  = lane & 15;
    const int quad = lane >> 4;
    const int n0   = wid * 16 + l15;       // this wave's N-column
    const float bb = bias[n0];

    floatx4 acc0 = {0.f, 0.f, 0.f, 0.f};   // m-tile 0 (rows 0..15)
    floatx4 acc1 = {0.f, 0.f, 0.f, 0.f};   // m-tile 1 (rows 16..31)
    #pragma unroll
    for (int kt = 0; kt < 4; ++kt) {
        int k0 = kt * 32 + quad * 8;
        short8 af0 = *(const short8*)&rowsbuf[l15 * 136 + k0];
        short8 af1 = *(const short8*)&rowsbuf[(l15 + 16) * 136 + k0];
        short8 bf  = *(const short8*)&wbf[n0 * DIM + k0];   // B[k][n]=W[n][k]
        acc0 = __builtin_amdgcn_mfma_f32_16x16x32_bf16(af0, bf, acc0, 0, 0, 0);
        acc1 = __builtin_amdgcn_mfma_f32_16x16x32_bf16(af1, bf, acc1, 0, 0, 0);
    }
    __syncthreads();               // rowsbuf dead

    // C/D layout: lane holds D[m=quad*4+r][n=l15] -> stage to Cbuf (+bias)
    #pragma unroll
    for (int r = 0; r < 4; ++r) {
        int m = quad * 4 + r;
        Cbuf[m * 132 + n0]        = acc0[r] + bb;
        Cbuf[(m + 16) * 132 + n0] = acc1[r] + bb;
    }
    __syncthreads();

    // ---- P5: ReLU + LN + scale/offset -> out (4 rows per wave) ----
    const float sc0 = scale[lane],  sc1 = scale[lane + 64];
    const float of0 = offset[lane], of1 = offset[lane + 64];

    #pragma unroll
    for (int j = 0; j < 4; ++j) {
        int rl = rb + j;
        int r  = hb * 32 + rl;
        if (r >= N_NODES) continue;                       // wave-uniform
        float A0 = fmaxf(Cbuf[rl * 132 + lane],      0.0f);
        float A1 = fmaxf(Cbuf[rl * 132 + lane + 64], 0.0f);

        float s = A0 + A1;
        #pragma unroll
        for (int off = 32; off >= 1; off >>= 1) s += __shfl_xor(s, off, 64);
        float mean = s * (1.0f / 128.0f);

        float d0 = A0 - mean, d1 = A1 - mean;
        float q2 = d0 * d0 + d1 * d1;
        #pragma unroll
        for (int off = 32; off >= 1; off >>= 1) q2 += __shfl_xor(q2, off, 64);
        float rstd = rsqrtf(q2 * (1.0f / 128.0f) + LN_EPS);

        size_t rowp = (size_t)r * DIM;
        out[rowp + lane]      = d0 * sc0 * rstd + of0;
        out[rowp + lane + 64] = d1 * sc1 * rstd + of1;
    }
}

extern "C" void kernel_launch(void* const* d_in, const int* in_sizes, int n_in,
                              void* d_out, int out_size, void* d_ws, size_t ws_size,
                              hipStream_t stream) {
    const float* feat_in = (const float*)d_in[0];
    const int*   rows    = (const int*)d_in[1];
    const int*   cols    = (const int*)d_in[2];
    const float* vals    = (const float*)d_in[3];
    const float* W       = (const float*)d_in[4];
    const float* bias    = (const float*)d_in[5];
    const float* scale   = (const float*)d_in[6];
    const float* offset  = (const float*)d_in[7];
    float* out = (float*)d_out;

    // ---- workspace layout ----
    char* p = (char*)d_ws;
    int2* perm = (int2*)p;                 p += (size_t)NB2 * CAP2 * 8;        // 16.0 MB
    ushort* featb = (ushort*)p;            p += (size_t)N_NODES * DIM * 2;     // 12.8 MB
    ushort* wbf = (ushort*)p;              p += DIM * DIM * 2;                 // 32 KB
    int*  gcnt = (int*)p;                  p += (size_t)(NB2 + 64) * 4;        // 6.4 KB

    hipMemsetAsync(gcnt, 0, (size_t)NB2 * sizeof(int), stream);

    prep<<<SB + CONVB, 1024, 0, stream>>>(feat_in, W, rows, cols, vals,
                                          gcnt, perm, (uint*)featb, wbf);
    agg_fused<<<NB2, 512, 0, stream>>>(perm, gcnt, featb, wbf,
                                       bias, scale, offset, out);
}

// Round 12
// 173.567 us; speedup vs baseline: 1.0721x; 1.0174x over previous
//
#include <hip/hip_runtime.h>

typedef unsigned int uint;
typedef unsigned short ushort;
typedef __attribute__((ext_vector_type(8))) short short8;   // 8 bf16 = 4 VGPRs
typedef __attribute__((ext_vector_type(4))) float floatx4;  // MFMA C/D

#define N_NODES 50000
#define N_EDGES 1600000
#define DIM 128
#define LN_EPS 1e-10f

#define NB2 1564                 // half-buckets of 32 rows: ceil(50000/32)
#define CAP2 1280                // mean 1024, +8 sigma
#define EPB 6250                 // edges per scatter block (256*6250 = 1.6M exact)
#define SB 256                   // scatter blocks
#define CONVB 256                // grid-stride convert blocks fused into prep
#define CAPR 76                  // per-row agg list slots (mean 32, +7.8 sigma)

__device__ __forceinline__ uint f2bf(float x) {
    uint u = __float_as_uint(x);
    return (u + 0x7FFFu + ((u >> 16) & 1u)) >> 16;   // RNE to bf16
}

// ---------------------------------------------------------------------------
// prep (R30 = R24 verbatim -- the measured-best prep; rest=110.3us across
// seven structural variants; stop touching it).  Fused scatter + grid-stride
// convert, register edge stash, 69 KB LDS -> 2 blocks/CU, line-rotated
// phase-B reservation atomics.
// ---------------------------------------------------------------------------
__global__ __launch_bounds__(1024, 8) void prep(
    const float* __restrict__ feat, const float* __restrict__ W,
    const int* __restrict__ rows, const int* __restrict__ cols,
    const float* __restrict__ vals, int* __restrict__ gcnt,
    int2* __restrict__ perm, uint* __restrict__ featb_u,
    ushort* __restrict__ wbf)
{
    __shared__ int  cnt[NB2];           // 6.3 KB
    __shared__ int  gbase[NB2];         // 6.3 KB
    __shared__ int  lbase[NB2];         // 6.3 KB
    __shared__ int  csum[64];
    __shared__ int2 stageE[EPB];        // 50 KB   (total 69 KB -> 2 blocks/CU)
    const int bx = blockIdx.x;
    const int t  = threadIdx.x;

    if (bx >= SB) {                      // ---- fused convert (no LDS use) ----
        const int cb = bx - SB;
        const int stride = CONVB * 1024;
        for (int i = cb * 1024 + t; i < N_NODES * DIM / 4; i += stride) {
            float4 v = ((const float4*)feat)[i];
            ((uint2*)featb_u)[i] = make_uint2(
                f2bf(v.x) | (f2bf(v.y) << 16),
                f2bf(v.z) | (f2bf(v.w) << 16));
        }
        for (int i = cb * 1024 + t; i < DIM * DIM / 4; i += stride) {
            float4 v = ((const float4*)W)[i];
            ushort4 o;
            o.x = (ushort)f2bf(v.x); o.y = (ushort)f2bf(v.y);
            o.z = (ushort)f2bf(v.z); o.w = (ushort)f2bf(v.w);
            ((ushort4*)wbf)[i] = o;
        }
        return;
    }

    // ---- phase A: rows -> rank-within-bin, stashed in registers ----
    for (int i = t; i < NB2; i += 1024) cnt[i] = 0;
    __syncthreads();
    const int base = bx * EPB;
    uint pk[7];                          // EPB = 6*1024 + 106
    #pragma unroll
    for (int i = 0; i < 7; ++i) {
        int k = i * 1024 + t;
        if (k < EPB) {
            int r = rows[base + k];
            int rank = atomicAdd(&cnt[r >> 5], 1);  // rank < 6250 (13 bits)
            pk[i] = ((uint)rank << 16) | (uint)r;   // r < 50000 (16 bits)
        }
    }
    __syncthreads();

    // ---- phase B: global reservation (line-rotated) + LDS scan (64x25) ----
    {
        const int rot = (bx * 16) % NB2;             // 64 B line offset/block
        for (int i = t; i < NB2; i += 1024) {
            int ii = i + rot; if (ii >= NB2) ii -= NB2;
            int c = cnt[ii];
            gbase[ii] = c ? atomicAdd(&gcnt[ii], c) : 0;
        }
    }
    if (t < 64) {
        int s = 0;
        for (int j = 0; j < 25; ++j) {
            int idx = t * 25 + j;
            if (idx < NB2) s += cnt[idx];
        }
        csum[t] = s;
    }
    __syncthreads();
    if (t == 0) {
        int s = 0;
        for (int i = 0; i < 64; ++i) { int c = csum[i]; csum[i] = s; s += c; }
    }
    __syncthreads();
    if (t < 64) {
        int run = csum[t];
        for (int j = 0; j < 25; ++j) {
            int idx = t * 25 + j;
            if (idx < NB2) { lbase[idx] = run; run += cnt[idx]; }
        }
    }
    __syncthreads();

    // ---- phase C: stage grouped by bin -- atomic-free placement ----
    // pack: col (16b) | local row r&31 (5b, bits 16-20) | bin (11b, bits 21-31)
    #pragma unroll
    for (int i = 0; i < 7; ++i) {
        int k = i * 1024 + t;
        if (k < EPB) {
            uint s = pk[i];
            int r = (int)(s & 0xFFFFu);
            int rank = (int)(s >> 16);
            int b = r >> 5;
            int pos = lbase[b] + rank;
            stageE[pos] = make_int2(
                (uint)cols[base + k] | ((uint)(r & 31) << 16) | ((uint)b << 21),
                __float_as_int(vals[base + k]));
        }
    }
    __syncthreads();

    // ---- phase D: clustered flush (slot order == destination order) ----
    for (int j = t; j < EPB; j += 1024) {
        int2 p = stageE[j];
        uint b = ((uint)p.x) >> 21;
        int pos = gbase[b] + (j - lbase[b]);
        if (pos < CAP2)                 // statistically impossible; safety
            perm[(size_t)b * CAP2 + pos] = p;       // agg masks b bits
    }
}

// ---------------------------------------------------------------------------
// agg_fused (R30): R29's P2 body (8x upfront int4 list reads, 16-edge chunk
// -- measured 18% MORE efficient per wave: 68.0us x 24 waves = 1632 wave-us
// vs R24's 60.4 x 32 = 1933) at R24's occupancy (__launch_bounds__(512,8),
// 4 blocks/CU, 32 waves).  R29 lost only because min-waves-6 cut occupancy
// 25% in the same round as the P2 change; this recombines the winning
// halves.  VGPR ~36 fits the 64-reg cap.  All else R24-identical.
// P1 stores BYTE offsets (col<<8); P3 LDS stride 136; P4 MFMA 16x16x32;
// P5 fused ReLU+LN.
// ---------------------------------------------------------------------------
__global__ __launch_bounds__(512, 8) void agg_fused(
    const int2* __restrict__ perm, const int* __restrict__ gcnt,
    const ushort* __restrict__ featb, const ushort* __restrict__ wbf,
    const float* __restrict__ bias, const float* __restrict__ scale,
    const float* __restrict__ offset, float* __restrict__ out)
{
    __shared__ int2 lists[32 * CAPR];    // 19456 B union:
    ushort* rowsbuf = (ushort*)lists;    //   P3/P4: 32 x 136 bf16 (8704 B)
    float*  Cbuf    = (float*)lists;     //   P5:    32 x 132 fp32 (16896 B)
    __shared__ int  lcnt[32];

    const int t = threadIdx.x;

    // bijective XCD-chunked swizzle: each XCD gets a contiguous bin range
    const int q = NB2 >> 3, rr = NB2 & 7;
    const int xcd = blockIdx.x & 7, within = blockIdx.x >> 3;
    const int hb = (xcd < rr ? xcd * (q + 1) : rr * (q + 1) + (xcd - rr) * q) + within;

    if (t < 32) lcnt[t] = 0;
    __syncthreads();

    int n = gcnt[hb];
    if (n > CAP2) n = CAP2;
    const int2* pb = perm + (size_t)hb * CAP2;

    // ---- P1: compaction (store byte offset col<<8 for cheap P2 addr) ----
    for (int e = t; e < n; e += 512) {
        int2 p = pb[e];
        int rl = (p.x >> 16) & 31;
        int pos = atomicAdd(&lcnt[rl], 1);
        if (pos < CAPR)
            lists[rl * CAPR + pos] = make_int2((p.x & 0xFFFF) << 8, p.y);
    }
    __syncthreads();

    const int lane = t & 63;
    const int wid  = t >> 6;        // 0..7
    const int rb   = wid * 4;       // this wave's first local row
    const char* fbase = (const char*)featb;
    const uint  lane4 = (uint)lane << 2;

    // ---- P2: gather + accumulate (ax = elem 2*lane, ay = elem 2*lane+1),
    //      16-edge chunks with 8 upfront int4 list reads (R29 body) ----
    float ax[4], ay[4];
    #pragma unroll
    for (int j = 0; j < 4; ++j) {
        int rl = rb + j;
        int cnt = lcnt[rl];
        if (cnt > CAPR) cnt = CAPR;
        const int2* L = &lists[rl * CAPR];
        float sx = 0.f, sy = 0.f;
        int e = 0;
        for (; e + 15 < cnt; e += 16) {           // 16-edge chunk
            int4 q8[8]; uint g[16];
            #pragma unroll
            for (int k = 0; k < 8; ++k) q8[k] = *(const int4*)&L[e + 2 * k];
            #pragma unroll
            for (int k = 0; k < 8; ++k) {
                g[2*k]   = *(const uint*)(fbase + ((uint)q8[k].x + lane4));
                g[2*k+1] = *(const uint*)(fbase + ((uint)q8[k].z + lane4));
            }
            #pragma unroll
            for (int k = 0; k < 8; ++k) {
                float v0 = __int_as_float(q8[k].y);
                float v1 = __int_as_float(q8[k].w);
                sx = fmaf(v0, __uint_as_float(g[2*k] << 16), sx);
                sy = fmaf(v0, __uint_as_float(g[2*k] & 0xFFFF0000u), sy);
                sx = fmaf(v1, __uint_as_float(g[2*k+1] << 16), sx);
                sy = fmaf(v1, __uint_as_float(g[2*k+1] & 0xFFFF0000u), sy);
            }
        }
        for (; e + 3 < cnt; e += 4) {
            int4 q2[2]; uint g[4];
            #pragma unroll
            for (int k = 0; k < 2; ++k) q2[k] = *(const int4*)&L[e + 2 * k];
            #pragma unroll
            for (int k = 0; k < 2; ++k) {
                g[2*k]   = *(const uint*)(fbase + ((uint)q2[k].x + lane4));
                g[2*k+1] = *(const uint*)(fbase + ((uint)q2[k].z + lane4));
            }
            #pragma unroll
            for (int k = 0; k < 2; ++k) {
                float v0 = __int_as_float(q2[k].y);
                float v1 = __int_as_float(q2[k].w);
                sx = fmaf(v0, __uint_as_float(g[2*k] << 16), sx);
                sy = fmaf(v0, __uint_as_float(g[2*k] & 0xFFFF0000u), sy);
                sx = fmaf(v1, __uint_as_float(g[2*k+1] << 16), sx);
                sy = fmaf(v1, __uint_as_float(g[2*k+1] & 0xFFFF0000u), sy);
            }
        }
        for (; e < cnt; ++e) {
            int2 p = L[e];
            uint g = *(const uint*)(fbase + ((uint)p.x + lane4));
            float v = __int_as_float(p.y);
            sx = fmaf(v, __uint_as_float(g << 16), sx);
            sy = fmaf(v, __uint_as_float(g & 0xFFFF0000u), sy);
        }
        ax[j] = sx; ay[j] = sy;
    }
    __syncthreads();               // lists dead

    // ---- P3: rows -> LDS bf16 (true element order), stride 136 ushorts ----
    #pragma unroll
    for (int j = 0; j < 4; ++j) {
        uint pkd = f2bf(ax[j]) | (f2bf(ay[j]) << 16);
        *(uint*)&rowsbuf[(rb + j) * 136 + 2 * lane] = pkd;
    }
    __syncthreads();

    // ---- P4: MFMA GEMM.  D[m][n] = sum_k A[m][k] * W[n][k] ----
    const int l15  = lane & 15;
    const int quad = lane >> 4;
    const int n0   = wid * 16 + l15;       // this wave's N-column
    const float bb = bias[n0];

    floatx4 acc0 = {0.f, 0.f, 0.f, 0.f};   // m-tile 0 (rows 0..15)
    floatx4 acc1 = {0.f, 0.f, 0.f, 0.f};   // m-tile 1 (rows 16..31)
    #pragma unroll
    for (int kt = 0; kt < 4; ++kt) {
        int k0 = kt * 32 + quad * 8;
        short8 af0 = *(const short8*)&rowsbuf[l15 * 136 + k0];
        short8 af1 = *(const short8*)&rowsbuf[(l15 + 16) * 136 + k0];
        short8 bf  = *(const short8*)&wbf[n0 * DIM + k0];   // B[k][n]=W[n][k]
        acc0 = __builtin_amdgcn_mfma_f32_16x16x32_bf16(af0, bf, acc0, 0, 0, 0);
        acc1 = __builtin_amdgcn_mfma_f32_16x16x32_bf16(af1, bf, acc1, 0, 0, 0);
    }
    __syncthreads();               // rowsbuf dead

    // C/D layout: lane holds D[m=quad*4+r][n=l15] -> stage to Cbuf (+bias)
    #pragma unroll
    for (int r = 0; r < 4; ++r) {
        int m = quad * 4 + r;
        Cbuf[m * 132 + n0]        = acc0[r] + bb;
        Cbuf[(m + 16) * 132 + n0] = acc1[r] + bb;
    }
    __syncthreads();

    // ---- P5: ReLU + LN + scale/offset -> out (4 rows per wave) ----
    const float sc0 = scale[lane],  sc1 = scale[lane + 64];
    const float of0 = offset[lane], of1 = offset[lane + 64];

    #pragma unroll
    for (int j = 0; j < 4; ++j) {
        int rl = rb + j;
        int r  = hb * 32 + rl;
        if (r >= N_NODES) continue;                       // wave-uniform
        float A0 = fmaxf(Cbuf[rl * 132 + lane],      0.0f);
        float A1 = fmaxf(Cbuf[rl * 132 + lane + 64], 0.0f);

        float s = A0 + A1;
        #pragma unroll
        for (int off = 32; off >= 1; off >>= 1) s += __shfl_xor(s, off, 64);
        float mean = s * (1.0f / 128.0f);

        float d0 = A0 - mean, d1 = A1 - mean;
        float q2 = d0 * d0 + d1 * d1;
        #pragma unroll
        for (int off = 32; off >= 1; off >>= 1) q2 += __shfl_xor(q2, off, 64);
        float rstd = rsqrtf(q2 * (1.0f / 128.0f) + LN_EPS);

        size_t rowp = (size_t)r * DIM;
        out[rowp + lane]      = d0 * sc0 * rstd + of0;
        out[rowp + lane + 64] = d1 * sc1 * rstd + of1;
    }
}

extern "C" void kernel_launch(void* const* d_in, const int* in_sizes, int n_in,
                              void* d_out, int out_size, void* d_ws, size_t ws_size,
                              hipStream_t stream) {
    const float* feat_in = (const float*)d_in[0];
    const int*   rows    = (const int*)d_in[1];
    const int*   cols    = (const int*)d_in[2];
    const float* vals    = (const float*)d_in[3];
    const float* W       = (const float*)d_in[4];
    const float* bias    = (const float*)d_in[5];
    const float* scale   = (const float*)d_in[6];
    const float* offset  = (const float*)d_in[7];
    float* out = (float*)d_out;

    // ---- workspace layout ----
    char* p = (char*)d_ws;
    int2* perm = (int2*)p;                 p += (size_t)NB2 * CAP2 * 8;        // 16.0 MB
    ushort* featb = (ushort*)p;            p += (size_t)N_NODES * DIM * 2;     // 12.8 MB
    ushort* wbf = (ushort*)p;              p += DIM * DIM * 2;                 // 32 KB
    int*  gcnt = (int*)p;                  p += (size_t)(NB2 + 64) * 4;        // 6.4 KB

    hipMemsetAsync(gcnt, 0, (size_t)NB2 * sizeof(int), stream);

    prep<<<SB + CONVB, 1024, 0, stream>>>(feat_in, W, rows, cols, vals,
                                          gcnt, perm, (uint*)featb, wbf);
    agg_fused<<<NB2, 512, 0, stream>>>(perm, gcnt, featb, wbf,
                                       bias, scale, offset, out);
}

// Round 13
// 164.246 us; speedup vs baseline: 1.1329x; 1.0568x over previous
//
#include <hip/hip_runtime.h>

typedef unsigned int uint;
typedef unsigned short ushort;
typedef unsigned long long ullong;
typedef __attribute__((ext_vector_type(8))) short short8;   // 8 bf16 = 4 VGPRs
typedef __attribute__((ext_vector_type(4))) float floatx4;  // MFMA C/D

#define N_NODES 50000
#define N_EDGES 1600000
#define DIM 128
#define LN_EPS 1e-10f

#define NB2 1564                 // half-buckets of 32 rows: ceil(50000/32)
#define CAP2 1280                // mean 1024, +8 sigma
#define EPB 6250                 // edges per scatter block (256*6250 = 1.6M exact)
#define SB 256                   // scatter blocks
#define CONVB 256                // grid-stride convert blocks fused into prep
#define CAPR 76                  // per-row agg list slots (mean 32, +7.8 sigma)

__device__ __forceinline__ uint f2bf(float x) {
    uint u = __float_as_uint(x);
    return (u + 0x7FFFu + ((u >> 16) & 1u)) >> 16;   // RNE to bf16
}

// ---------------------------------------------------------------------------
// prep (R31 = R24 verbatim -- the measured-best prep; rest=110.3us across
// seven structural variants; frozen).  Fused scatter + grid-stride convert,
// register edge stash, 69 KB LDS -> 2 blocks/CU, line-rotated phase-B
// reservation atomics.
// ---------------------------------------------------------------------------
__global__ __launch_bounds__(1024, 8) void prep(
    const float* __restrict__ feat, const float* __restrict__ W,
    const int* __restrict__ rows, const int* __restrict__ cols,
    const float* __restrict__ vals, int* __restrict__ gcnt,
    int2* __restrict__ perm, uint* __restrict__ featb_u,
    ushort* __restrict__ wbf)
{
    __shared__ int  cnt[NB2];           // 6.3 KB
    __shared__ int  gbase[NB2];         // 6.3 KB
    __shared__ int  lbase[NB2];         // 6.3 KB
    __shared__ int  csum[64];
    __shared__ int2 stageE[EPB];        // 50 KB   (total 69 KB -> 2 blocks/CU)
    const int bx = blockIdx.x;
    const int t  = threadIdx.x;

    if (bx >= SB) {                      // ---- fused convert (no LDS use) ----
        const int cb = bx - SB;
        const int stride = CONVB * 1024;
        for (int i = cb * 1024 + t; i < N_NODES * DIM / 4; i += stride) {
            float4 v = ((const float4*)feat)[i];
            ((uint2*)featb_u)[i] = make_uint2(
                f2bf(v.x) | (f2bf(v.y) << 16),
                f2bf(v.z) | (f2bf(v.w) << 16));
        }
        for (int i = cb * 1024 + t; i < DIM * DIM / 4; i += stride) {
            float4 v = ((const float4*)W)[i];
            ushort4 o;
            o.x = (ushort)f2bf(v.x); o.y = (ushort)f2bf(v.y);
            o.z = (ushort)f2bf(v.z); o.w = (ushort)f2bf(v.w);
            ((ushort4*)wbf)[i] = o;
        }
        return;
    }

    // ---- phase A: rows -> rank-within-bin, stashed in registers ----
    for (int i = t; i < NB2; i += 1024) cnt[i] = 0;
    __syncthreads();
    const int base = bx * EPB;
    uint pk[7];                          // EPB = 6*1024 + 106
    #pragma unroll
    for (int i = 0; i < 7; ++i) {
        int k = i * 1024 + t;
        if (k < EPB) {
            int r = rows[base + k];
            int rank = atomicAdd(&cnt[r >> 5], 1);  // rank < 6250 (13 bits)
            pk[i] = ((uint)rank << 16) | (uint)r;   // r < 50000 (16 bits)
        }
    }
    __syncthreads();

    // ---- phase B: global reservation (line-rotated) + LDS scan (64x25) ----
    {
        const int rot = (bx * 16) % NB2;             // 64 B line offset/block
        for (int i = t; i < NB2; i += 1024) {
            int ii = i + rot; if (ii >= NB2) ii -= NB2;
            int c = cnt[ii];
            gbase[ii] = c ? atomicAdd(&gcnt[ii], c) : 0;
        }
    }
    if (t < 64) {
        int s = 0;
        for (int j = 0; j < 25; ++j) {
            int idx = t * 25 + j;
            if (idx < NB2) s += cnt[idx];
        }
        csum[t] = s;
    }
    __syncthreads();
    if (t == 0) {
        int s = 0;
        for (int i = 0; i < 64; ++i) { int c = csum[i]; csum[i] = s; s += c; }
    }
    __syncthreads();
    if (t < 64) {
        int run = csum[t];
        for (int j = 0; j < 25; ++j) {
            int idx = t * 25 + j;
            if (idx < NB2) { lbase[idx] = run; run += cnt[idx]; }
        }
    }
    __syncthreads();

    // ---- phase C: stage grouped by bin -- atomic-free placement ----
    // pack: col (16b) | local row r&31 (5b, bits 16-20) | bin (11b, bits 21-31)
    #pragma unroll
    for (int i = 0; i < 7; ++i) {
        int k = i * 1024 + t;
        if (k < EPB) {
            uint s = pk[i];
            int r = (int)(s & 0xFFFFu);
            int rank = (int)(s >> 16);
            int b = r >> 5;
            int pos = lbase[b] + rank;
            stageE[pos] = make_int2(
                (uint)cols[base + k] | ((uint)(r & 31) << 16) | ((uint)b << 21),
                __float_as_int(vals[base + k]));
        }
    }
    __syncthreads();

    // ---- phase D: clustered flush (slot order == destination order) ----
    for (int j = t; j < EPB; j += 1024) {
        int2 p = stageE[j];
        uint b = ((uint)p.x) >> 21;
        int pos = gbase[b] + (j - lbase[b]);
        if (pos < CAP2)                 // statistically impossible; safety
            perm[(size_t)b * CAP2 + pos] = p;       // agg masks b bits
    }
}

// ---------------------------------------------------------------------------
// agg_fused (R31 = R24 agg + NON-TEMPORAL hints on the two single-use
// streams).  Theory: featb (12.8 MB, re-read 410MB logical -> 64% L2 hit)
// shares L2 with perm (12.8 MB read ONCE) and out (25 MB written once,
// never read); every perm/out line allocated evicts a hot featb line.
// P1 perm reads use __builtin_nontemporal_load; P5 out stores use
// __builtin_nontemporal_store.  Everything else byte-identical to R24
// (12-deep P2 chunk, (512,8) bounds, XCD swizzle, stride-136 LDS).
// P2 depth question is CLOSED: compiler holds ~8 real outstanding loads
// regardless of source chunking (R28/R29/R30 all regressed).
// ---------------------------------------------------------------------------
__global__ __launch_bounds__(512, 8) void agg_fused(
    const int2* __restrict__ perm, const int* __restrict__ gcnt,
    const ushort* __restrict__ featb, const ushort* __restrict__ wbf,
    const float* __restrict__ bias, const float* __restrict__ scale,
    const float* __restrict__ offset, float* __restrict__ out)
{
    __shared__ int2 lists[32 * CAPR];    // 19456 B union:
    ushort* rowsbuf = (ushort*)lists;    //   P3/P4: 32 x 136 bf16 (8704 B)
    float*  Cbuf    = (float*)lists;     //   P5:    32 x 132 fp32 (16896 B)
    __shared__ int  lcnt[32];

    const int t = threadIdx.x;

    // bijective XCD-chunked swizzle: each XCD gets a contiguous bin range
    const int q = NB2 >> 3, rr = NB2 & 7;
    const int xcd = blockIdx.x & 7, within = blockIdx.x >> 3;
    const int hb = (xcd < rr ? xcd * (q + 1) : rr * (q + 1) + (xcd - rr) * q) + within;

    if (t < 32) lcnt[t] = 0;
    __syncthreads();

    int n = gcnt[hb];
    if (n > CAP2) n = CAP2;
    const int2* pb = perm + (size_t)hb * CAP2;

    // ---- P1: compaction; perm is single-use -> non-temporal load ----
    for (int e = t; e < n; e += 512) {
        ullong pv = __builtin_nontemporal_load((const ullong*)&pb[e]);
        int px = (int)(uint)pv;
        int py = (int)(uint)(pv >> 32);
        int rl = (px >> 16) & 31;
        int pos = atomicAdd(&lcnt[rl], 1);
        if (pos < CAPR)
            lists[rl * CAPR + pos] = make_int2((px & 0xFFFF) << 8, py);
    }
    __syncthreads();

    const int lane = t & 63;
    const int wid  = t >> 6;        // 0..7
    const int rb   = wid * 4;       // this wave's first local row
    const char* fbase = (const char*)featb;
    const uint  lane4 = (uint)lane << 2;

    // ---- P2: gather + accumulate (ax = elem 2*lane, ay = elem 2*lane+1) ----
    float ax[4], ay[4];
    #pragma unroll
    for (int j = 0; j < 4; ++j) {
        int rl = rb + j;
        int cnt = lcnt[rl];
        if (cnt > CAPR) cnt = CAPR;
        const int2* L = &lists[rl * CAPR];
        float sx = 0.f, sy = 0.f;
        int e = 0;
        for (; e + 11 < cnt; e += 12) {           // 12 outstanding gathers
            int4 q6[6]; uint g[12];
            #pragma unroll
            for (int k = 0; k < 6; ++k) q6[k] = *(const int4*)&L[e + 2 * k];
            #pragma unroll
            for (int k = 0; k < 6; ++k) {
                g[2*k]   = *(const uint*)(fbase + ((uint)q6[k].x + lane4));
                g[2*k+1] = *(const uint*)(fbase + ((uint)q6[k].z + lane4));
            }
            #pragma unroll
            for (int k = 0; k < 6; ++k) {
                float v0 = __int_as_float(q6[k].y);
                float v1 = __int_as_float(q6[k].w);
                sx = fmaf(v0, __uint_as_float(g[2*k] << 16), sx);
                sy = fmaf(v0, __uint_as_float(g[2*k] & 0xFFFF0000u), sy);
                sx = fmaf(v1, __uint_as_float(g[2*k+1] << 16), sx);
                sy = fmaf(v1, __uint_as_float(g[2*k+1] & 0xFFFF0000u), sy);
            }
        }
        for (; e + 3 < cnt; e += 4) {
            int4 q2[2]; uint g[4];
            #pragma unroll
            for (int k = 0; k < 2; ++k) q2[k] = *(const int4*)&L[e + 2 * k];
            #pragma unroll
            for (int k = 0; k < 2; ++k) {
                g[2*k]   = *(const uint*)(fbase + ((uint)q2[k].x + lane4));
                g[2*k+1] = *(const uint*)(fbase + ((uint)q2[k].z + lane4));
            }
            #pragma unroll
            for (int k = 0; k < 2; ++k) {
                float v0 = __int_as_float(q2[k].y);
                float v1 = __int_as_float(q2[k].w);
                sx = fmaf(v0, __uint_as_float(g[2*k] << 16), sx);
                sy = fmaf(v0, __uint_as_float(g[2*k] & 0xFFFF0000u), sy);
                sx = fmaf(v1, __uint_as_float(g[2*k+1] << 16), sx);
                sy = fmaf(v1, __uint_as_float(g[2*k+1] & 0xFFFF0000u), sy);
            }
        }
        for (; e < cnt; ++e) {
            int2 p = L[e];
            uint g = *(const uint*)(fbase + ((uint)p.x + lane4));
            float v = __int_as_float(p.y);
            sx = fmaf(v, __uint_as_float(g << 16), sx);
            sy = fmaf(v, __uint_as_float(g & 0xFFFF0000u), sy);
        }
        ax[j] = sx; ay[j] = sy;
    }
    __syncthreads();               // lists dead

    // ---- P3: rows -> LDS bf16 (true element order), stride 136 ushorts ----
    #pragma unroll
    for (int j = 0; j < 4; ++j) {
        uint pkd = f2bf(ax[j]) | (f2bf(ay[j]) << 16);
        *(uint*)&rowsbuf[(rb + j) * 136 + 2 * lane] = pkd;
    }
    __syncthreads();

    // ---- P4: MFMA GEMM.  D[m][n] = sum_k A[m][k] * W[n][k] ----
    const int l15  = lane & 15;
    const int quad = lane >> 4;
    const int n0   = wid * 16 + l15;       // this wave's N-column
    const float bb = bias[n0];

    floatx4 acc0 = {0.f, 0.f, 0.f, 0.f};   // m-tile 0 (rows 0..15)
    floatx4 acc1 = {0.f, 0.f, 0.f, 0.f};   // m-tile 1 (rows 16..31)
    #pragma unroll
    for (int kt = 0; kt < 4; ++kt) {
        int k0 = kt * 32 + quad * 8;
        short8 af0 = *(const short8*)&rowsbuf[l15 * 136 + k0];
        short8 af1 = *(const short8*)&rowsbuf[(l15 + 16) * 136 + k0];
        short8 bf  = *(const short8*)&wbf[n0 * DIM + k0];   // B[k][n]=W[n][k]
        acc0 = __builtin_amdgcn_mfma_f32_16x16x32_bf16(af0, bf, acc0, 0, 0, 0);
        acc1 = __builtin_amdgcn_mfma_f32_16x16x32_bf16(af1, bf, acc1, 0, 0, 0);
    }
    __syncthreads();               // rowsbuf dead

    // C/D layout: lane holds D[m=quad*4+r][n=l15] -> stage to Cbuf (+bias)
    #pragma unroll
    for (int r = 0; r < 4; ++r) {
        int m = quad * 4 + r;
        Cbuf[m * 132 + n0]        = acc0[r] + bb;
        Cbuf[(m + 16) * 132 + n0] = acc1[r] + bb;
    }
    __syncthreads();

    // ---- P5: ReLU + LN + scale/offset -> out (write-once: NT stores) ----
    const float sc0 = scale[lane],  sc1 = scale[lane + 64];
    const float of0 = offset[lane], of1 = offset[lane + 64];

    #pragma unroll
    for (int j = 0; j < 4; ++j) {
        int rl = rb + j;
        int r  = hb * 32 + rl;
        if (r >= N_NODES) continue;                       // wave-uniform
        float A0 = fmaxf(Cbuf[rl * 132 + lane],      0.0f);
        float A1 = fmaxf(Cbuf[rl * 132 + lane + 64], 0.0f);

        float s = A0 + A1;
        #pragma unroll
        for (int off = 32; off >= 1; off >>= 1) s += __shfl_xor(s, off, 64);
        float mean = s * (1.0f / 128.0f);

        float d0 = A0 - mean, d1 = A1 - mean;
        float q2 = d0 * d0 + d1 * d1;
        #pragma unroll
        for (int off = 32; off >= 1; off >>= 1) q2 += __shfl_xor(q2, off, 64);
        float rstd = rsqrtf(q2 * (1.0f / 128.0f) + LN_EPS);

        size_t rowp = (size_t)r * DIM;
        __builtin_nontemporal_store(d0 * sc0 * rstd + of0, &out[rowp + lane]);
        __builtin_nontemporal_store(d1 * sc1 * rstd + of1, &out[rowp + lane + 64]);
    }
}

extern "C" void kernel_launch(void* const* d_in, const int* in_sizes, int n_in,
                              void* d_out, int out_size, void* d_ws, size_t ws_size,
                              hipStream_t stream) {
    const float* feat_in = (const float*)d_in[0];
    const int*   rows    = (const int*)d_in[1];
    const int*   cols    = (const int*)d_in[2];
    const float* vals    = (const float*)d_in[3];
    const float* W       = (const float*)d_in[4];
    const float* bias    = (const float*)d_in[5];
    const float* scale   = (const float*)d_in[6];
    const float* offset  = (const float*)d_in[7];
    float* out = (float*)d_out;

    // ---- workspace layout ----
    char* p = (char*)d_ws;
    int2* perm = (int2*)p;                 p += (size_t)NB2 * CAP2 * 8;        // 16.0 MB
    ushort* featb = (ushort*)p;            p += (size_t)N_NODES * DIM * 2;     // 12.8 MB
    ushort* wbf = (ushort*)p;              p += DIM * DIM * 2;                 // 32 KB
    int*  gcnt = (int*)p;                  p += (size_t)(NB2 + 64) * 4;        // 6.4 KB

    hipMemsetAsync(gcnt, 0, (size_t)NB2 * sizeof(int), stream);

    prep<<<SB + CONVB, 1024, 0, stream>>>(feat_in, W, rows, cols, vals,
                                          gcnt, perm, (uint*)featb, wbf);
    agg_fused<<<NB2, 512, 0, stream>>>(perm, gcnt, featb, wbf,
                                       bias, scale, offset, out);
}